// Round 1
// baseline (249.475 us; speedup 1.0000x reference)
//
#include <hip/hip_runtime.h>
#include <hip/hip_bf16.h>
#include <math.h>

// Problem constants (from reference)
#define MSEG  4096     // number of graphs / segments
#define NNODE 262144   // total nodes
#define DDIM  128      // d_h == d_x == 128
#define CHUNK 64       // nodes per LDS chunk (avg segment size is 64)

__device__ __forceinline__ int lower_bound_dev(const int* __restrict__ seg, int n, int val) {
    int lo = 0, hi = n;
    while (lo < hi) {
        int mid = (lo + hi) >> 1;
        if (seg[mid] < val) lo = mid + 1; else hi = mid;
    }
    return lo;
}

// One block per segment. 256 threads.
// Phase 0: block computes proj[g] = h[g] @ a (128 floats) into LDS; threads 0,1
//          binary-search the segment bounds (segment_ids is sorted).
// Phase 1: stream nodes in CHUNK-sized pieces:
//   - coalesced float4 loads of x rows -> LDS, fused with score partials
//     (s_i = x_i . proj[g]), reduced per-node over 32-lane groups.
//   - online softmax: chunk max (wave0 reduce), e_i = exp(s_i - m_new),
//     running (m, l), per-thread accumulator over (dim, parity).
// Phase 2: combine parities, out[g] = acc / l. Empty segments -> zeros.
__global__ __launch_bounds__(256) void attn_seg_kernel(
    const float* __restrict__ h,
    const float* __restrict__ x,
    const float* __restrict__ a,
    const int*   __restrict__ seg,
    float*       __restrict__ out)
{
    __shared__ __align__(16) float x_lds[CHUNK * DDIM];  // 32 KB chunk cache
    __shared__ float s_lds[CHUNK];                       // scores -> e values
    __shared__ float red[256];                           // reduction scratch
    __shared__ __align__(16) float proj_lds[DDIM];
    __shared__ float red2[2];                            // [0]=chunk max, [1]=chunk e-sum
    __shared__ int   bounds[2];

    const int g      = blockIdx.x;
    const int tid    = threadIdx.x;
    const int d      = tid & 127;   // owned feature dim
    const int parity = tid >> 7;    // node-parity for accumulation
    const int q      = tid & 31;    // float4-quad within a row
    const int c      = tid >> 5;    // 8 groups of 32 threads (load phase)

    // ---- Phase 0: proj[g] = h[g] @ a ------------------------------------
    {
        const int k0 = parity * 64;                 // halves of K
        const float* hg = h + (size_t)g * DDIM;
        float p = 0.f;
        #pragma unroll 8
        for (int k = 0; k < 64; ++k) {
            // a[k][d]: lanes read consecutive d -> coalesced; a stays L2-hot.
            p += hg[k0 + k] * a[(size_t)(k0 + k) * DDIM + d];
        }
        red[tid] = p;
    }
    if (tid < 2) bounds[tid] = lower_bound_dev(seg, NNODE, g + tid);
    __syncthreads();
    if (tid < 128) proj_lds[tid] = red[tid] + red[tid + 128];
    __syncthreads();

    const int start = bounds[0];
    const int end   = bounds[1];
    if (start >= end) {                              // empty segment -> zeros
        if (tid < DDIM) out[(size_t)g * DDIM + tid] = 0.f;
        return;
    }

    const float4 pj = ((const float4*)proj_lds)[q];  // chunk-invariant fragment
    const float4* __restrict__ xg4 = (const float4*)x;

    float m   = -INFINITY;  // running max   (uniform across threads)
    float l   = 0.f;        // running denom (uniform across threads)
    float acc = 0.f;        // partial of out[g][d] over nodes i ≡ parity (mod 2)

    for (int cs = start; cs < end; cs += CHUNK) {
        const int n_c = min(CHUNK, end - cs);

        // ---- load x rows to LDS, fused score partials -------------------
        #pragma unroll
        for (int j = 0; j < CHUNK / 8; ++j) {
            const int i = j * 8 + c;                 // local node index
            float ps = 0.f;
            if (i < n_c) {
                // nodes are contiguous: each wave reads 1 KB contiguous HBM
                float4 x4 = xg4[(size_t)(cs + i) * (DDIM / 4) + q];
                ((float4*)(x_lds + i * DDIM))[q] = x4;
                ps = x4.x * pj.x + x4.y * pj.y + x4.z * pj.z + x4.w * pj.w;
            }
            #pragma unroll
            for (int off = 16; off > 0; off >>= 1)   // 32-lane group reduce
                ps += __shfl_down(ps, off, 32);
            if (q == 0 && i < n_c) s_lds[i] = ps;
        }
        __syncthreads();

        // ---- chunk max (scores live in wave 0's range: n_c <= 64) -------
        if (tid < 64) {
            float v = (tid < n_c) ? s_lds[tid] : -INFINITY;
            #pragma unroll
            for (int off = 32; off > 0; off >>= 1)
                v = fmaxf(v, __shfl_down(v, off, 64));
            if (tid == 0) red2[0] = v;
        }
        __syncthreads();

        const float m_new = fmaxf(m, red2[0]);
        const float alpha = expf(m - m_new);         // exp(-inf)=0 on first chunk
        if (tid < 64) {
            float e = 0.f;
            if (tid < n_c) {
                e = expf(s_lds[tid] - m_new);
                s_lds[tid] = e;                      // in-place: s -> e
            }
            #pragma unroll
            for (int off = 32; off > 0; off >>= 1)
                e += __shfl_down(e, off, 64);
            if (tid == 0) red2[1] = e;
        }
        __syncthreads();

        l = l * alpha + red2[1];
        m = m_new;

        // ---- weighted accumulation from LDS -----------------------------
        acc *= alpha;
        for (int i = parity; i < n_c; i += 2) {
            // s_lds[i]: broadcast; x_lds row read: consecutive d, conflict-free
            acc += s_lds[i] * x_lds[i * DDIM + d];
        }
        __syncthreads();  // protect x_lds/s_lds before next chunk
    }

    // ---- Phase 2: combine parities, normalize, store --------------------
    red[tid] = acc;
    __syncthreads();
    if (tid < 128) {
        out[(size_t)g * DDIM + tid] = (red[tid] + red[tid + 128]) / l;
    }
}

extern "C" void kernel_launch(void* const* d_in, const int* in_sizes, int n_in,
                              void* d_out, int out_size, void* d_ws, size_t ws_size,
                              hipStream_t stream) {
    const float* h   = (const float*)d_in[0];   // (M, DH)
    const float* x   = (const float*)d_in[1];   // (N, DX)
    const float* a   = (const float*)d_in[2];   // (DH, DX)
    const int*   seg = (const int*)  d_in[3];   // (N,) sorted
    float* out = (float*)d_out;                 // (M, DX)

    attn_seg_kernel<<<MSEG, 256, 0, stream>>>(h, x, a, seg, out);
}

// Round 2
// 209.706 us; speedup vs baseline: 1.1896x; 1.1896x over previous
//
#include <hip/hip_runtime.h>
#include <hip/hip_bf16.h>
#include <math.h>

// Problem constants (from reference)
#define MSEG  4096     // number of graphs / segments
#define NNODE 262144   // total nodes
#define DDIM  128      // d_h == d_x == 128
#define CHUNK 64       // nodes per register chunk (avg segment size is 64)

// Kernel 1: segment start offsets (segment_ids is sorted).
// starts[g] = first index i with seg[i] >= g; starts[MSEG] = NNODE.
// Covers empty segments (start==end). ~1 MB coalesced read, trivial cost.
__global__ __launch_bounds__(256) void seg_starts_kernel(
    const int* __restrict__ seg, int* __restrict__ starts)
{
    int i = blockIdx.x * blockDim.x + threadIdx.x;
    if (i >= NNODE) return;
    int s = seg[i];
    int prev = (i == 0) ? -1 : seg[i - 1];
    for (int g = prev + 1; g <= s; ++g) starts[g] = i;
    if (i == NNODE - 1)
        for (int g = s + 1; g <= MSEG; ++g) starts[g] = NNODE;
}

// Kernel 2: one block per segment, 256 threads.
// Thread (c = tid>>5, q = tid&31) owns rows i = c+8j (j<8) at dims [4q,4q+4).
// x rows live in REGISTERS (xv[8]) — loaded once, used for both the score
// dot-product and the weighted accumulation; no LDS staging of x.
// Online softmax state (m, l) is block-uniform, tracked redundantly per thread;
// softmax stats are computed redundantly per-wave (butterfly over 64 scores)
// so only 2 __syncthreads() per chunk are needed.
__global__ __launch_bounds__(256) void attn_seg_kernel(
    const float* __restrict__ h,
    const float* __restrict__ x,
    const float* __restrict__ a,
    const int*   __restrict__ starts,
    float*       __restrict__ out)
{
    __shared__ float s_lds[CHUNK];                    // raw scores of the chunk
    __shared__ float red[256];                        // proj reduction scratch
    __shared__ __align__(16) float proj_lds[DDIM];
    __shared__ __align__(16) float4 racc[256];        // final acc reduction (4 KB)

    const int g    = blockIdx.x;
    const int tid  = threadIdx.x;
    const int q    = tid & 31;
    const int c    = tid >> 5;
    const int lane = tid & 63;

    const int start = starts[g];
    const int end   = starts[g + 1];

    if (start >= end) {                               // empty segment -> zeros
        if (tid < DDIM) out[(size_t)g * DDIM + tid] = 0.f;
        return;
    }

    const float4* __restrict__ x4p = (const float4*)x;

    // ---- prefetch chunk 0 into registers (latency hides behind proj) ----
    int n_c = min(CHUNK, end - start);
    float4 xv[8];
    #pragma unroll
    for (int j = 0; j < 8; ++j) {
        const int i = j * 8 + c;
        xv[j] = make_float4(0.f, 0.f, 0.f, 0.f);
        if (i < n_c) xv[j] = x4p[(size_t)(start + i) * (DDIM / 4) + q];
    }

    // ---- proj[g] = h[g] @ a (h row is wave-uniform -> scalar loads; a is L2-hot)
    {
        const int half = tid >> 7;
        const int d    = tid & 127;
        const int k0   = half * 64;
        const float* hg = h + (size_t)g * DDIM;
        float p = 0.f;
        #pragma unroll 8
        for (int k = 0; k < 64; ++k)
            p += hg[k0 + k] * a[(size_t)(k0 + k) * DDIM + d];
        red[tid] = p;
    }
    __syncthreads();
    if (tid < 128) proj_lds[tid] = red[tid] + red[tid + 128];
    __syncthreads();

    const float4 pj = ((const float4*)proj_lds)[q];

    float m = -INFINITY;                              // running max (uniform)
    float l = 0.f;                                    // running denom (uniform)
    float4 acc = make_float4(0.f, 0.f, 0.f, 0.f);     // out[g][4q..4q+3], rows ≡ c (mod 8)

    int cs = start;
    while (true) {
        // ---- scores from registers: s_i = x_i . proj ---------------------
        #pragma unroll
        for (int j = 0; j < 8; ++j) {
            const int i = j * 8 + c;
            float ps = xv[j].x * pj.x + xv[j].y * pj.y
                     + xv[j].z * pj.z + xv[j].w * pj.w;
            #pragma unroll
            for (int off = 16; off > 0; off >>= 1)    // reduce over the 32-lane quad-group
                ps += __shfl_down(ps, off, 32);
            if (q == 0 && i < n_c) s_lds[i] = ps;
        }
        __syncthreads();

        // ---- softmax stats, redundantly per wave (no second barrier) -----
        float v = (lane < n_c) ? s_lds[lane] : -INFINITY;
        #pragma unroll
        for (int off = 32; off > 0; off >>= 1)        // 64-lane max butterfly
            v = fmaxf(v, __shfl_xor(v, off));
        const float m_new = fmaxf(m, v);
        float e = (lane < n_c) ? __expf(s_lds[lane] - m_new) : 0.f;
        #pragma unroll
        for (int off = 32; off > 0; off >>= 1)        // 64-lane sum butterfly
            e += __shfl_xor(e, off);

        const float alpha = __expf(m - m_new);        // exp(-inf)=0 on first chunk
        l = l * alpha + e;
        m = m_new;
        acc.x *= alpha; acc.y *= alpha; acc.z *= alpha; acc.w *= alpha;

        // ---- weighted accumulation from registers ------------------------
        // s_lds[i] is a broadcast read (all 32 lanes of the group, same addr).
        #pragma unroll
        for (int j = 0; j < 8; ++j) {
            const int i = j * 8 + c;
            if (i < n_c) {
                const float ei = __expf(s_lds[i] - m_new);
                acc.x += ei * xv[j].x;
                acc.y += ei * xv[j].y;
                acc.z += ei * xv[j].z;
                acc.w += ei * xv[j].w;
            }
        }

        cs += CHUNK;
        if (cs >= end) break;
        __syncthreads();                              // protect s_lds before rewrite
        n_c = min(CHUNK, end - cs);
        #pragma unroll
        for (int j = 0; j < 8; ++j) {
            const int i = j * 8 + c;
            xv[j] = make_float4(0.f, 0.f, 0.f, 0.f);
            if (i < n_c) xv[j] = x4p[(size_t)(cs + i) * (DDIM / 4) + q];
        }
    }

    // ---- final: reduce acc over the 8 row-groups, normalize, store -------
    racc[tid] = acc;
    __syncthreads();
    if (tid < 32) {
        float4 s = racc[tid];
        #pragma unroll
        for (int cc = 1; cc < 8; ++cc) {
            float4 t = racc[cc * 32 + tid];
            s.x += t.x; s.y += t.y; s.z += t.z; s.w += t.w;
        }
        const float inv = 1.f / l;
        ((float4*)out)[(size_t)g * 32 + tid] =
            make_float4(s.x * inv, s.y * inv, s.z * inv, s.w * inv);
    }
}

extern "C" void kernel_launch(void* const* d_in, const int* in_sizes, int n_in,
                              void* d_out, int out_size, void* d_ws, size_t ws_size,
                              hipStream_t stream) {
    const float* h   = (const float*)d_in[0];   // (M, DH)
    const float* x   = (const float*)d_in[1];   // (N, DX)
    const float* a   = (const float*)d_in[2];   // (DH, DX)
    const int*   seg = (const int*)  d_in[3];   // (N,) sorted
    float* out = (float*)d_out;                 // (M, DX)
    int*   starts = (int*)d_ws;                 // (MSEG+1,) scratch

    seg_starts_kernel<<<(NNODE + 255) / 256, 256, 0, stream>>>(seg, starts);
    attn_seg_kernel<<<MSEG, 256, 0, stream>>>(h, x, a, starts, out);
}